// Round 11
// baseline (422.898 us; speedup 1.0000x reference)
//
#include <hip/hip_runtime.h>
#include <hip/hip_bf16.h>
#include <stdint.h>

// ---------- types / helpers ----------
typedef __bf16 bf16x8_t __attribute__((ext_vector_type(8)));
typedef float f32x4_t __attribute__((ext_vector_type(4)));
typedef unsigned short ushort8_t __attribute__((ext_vector_type(8)));  // 16B aligned

__device__ __forceinline__ unsigned short f2bf(float f) {
    union { float f; uint32_t i; } v; v.f = f;
    uint32_t i = v.i + (((v.i >> 16) & 1u) + 0x7FFFu);   // RNE
    return (unsigned short)(i >> 16);
}

typedef const __attribute__((address_space(1))) void* gas_t;
typedef __attribute__((address_space(3))) void* las_t;
__device__ __forceinline__ void load_lds16(const unsigned short* g, unsigned short* l) {
    // async global->LDS DMA; LDS dest = wave-uniform base + lane*16B
    __builtin_amdgcn_global_load_lds((gas_t)g, (las_t)l, 16, 0, 0);
}

// ---------- problem constants ----------
#define BB   256
#define CC   3
#define HH   128
#define WW   128
#define PP   768        // C*K*K
#define HID  2048
#define LL   256
#define MM   16384      // B*GH*GW

// ---------- patchify: x f32 (B,C,H,W) -> patches bf16 (M,768), u16-view of out0 ----------
__global__ void patchify(const float* __restrict__ x,
                         unsigned short* __restrict__ patches) {
    int t = blockIdx.x * 256 + threadIdx.x;        // 1,572,864 threads, 8 elems each
    int e = t * 8;                                  // linear index into x
    int col = e & 127;                              // w (multiple of 8)
    int row = (e >> 7) & 127;                       // h
    int c   = (e >> 14) % 3;
    int b   = e / (128 * 128 * 3);
    int gh = row >> 4, kh = row & 15, gw = col >> 4, kw = col & 15;
    long po = (long)(b * 64 + gh * 8 + gw) * PP + c * 256 + kh * 16 + kw;
    float4 v0 = *(const float4*)(x + e);
    float4 v1 = *(const float4*)(x + e + 4);
    ushort8_t o;
    o[0] = f2bf(v0.x); o[1] = f2bf(v0.y); o[2] = f2bf(v0.z); o[3] = f2bf(v0.w);
    o[4] = f2bf(v1.x); o[5] = f2bf(v1.y); o[6] = f2bf(v1.z); o[7] = f2bf(v1.w);
    *(ushort8_t*)(patches + po) = o;
}

// ---------- 32x32-tiled transpose + cast: out bf16[c*R+r] = in f32[r*C+c] ----------
__global__ void transpose_k(const float* __restrict__ in,
                            unsigned short* __restrict__ out, int R, int C) {
    __shared__ unsigned short tile[32][34];
    int nbc = C >> 5;
    int tc = blockIdx.x % nbc, tr = blockIdx.x / nbc;
    int tx = threadIdx.x & 31, ty0 = threadIdx.x >> 5;   // 8 rows/pass
    int r0 = tr << 5, c0 = tc << 5;
    #pragma unroll
    for (int i = 0; i < 4; ++i) {
        int ty = ty0 + i * 8;
        tile[ty][tx] = f2bf(in[(long)(r0 + ty) * C + c0 + tx]);
    }
    __syncthreads();
    #pragma unroll
    for (int i = 0; i < 4; ++i) {
        int ty = ty0 + i * 8;
        out[(long)(c0 + ty) * R + r0 + tx] = tile[tx][ty];
    }
}

// ---------- GEMM: C(rows x N) = act(A(rows x K) @ Bt(N x K)^T + bias f32) ----------
// 256x256 macro-tile, BK=32 DOUBLE-BUFFERED, 512 thr = 8 waves (4x2); each
// wave 64x128 = 4x8 MFMA 16x16x32 bf16, fp32 acc. global_load_lds staging
// with additive swizzle phys_g=(g+(row>>1))&3 (2-way aliasing = free).
// Stage(next buf) issued BEFORE compute(cur) -> DMA latency hidden under
// ~1240 cyc of MFMA; single barrier per K-iter. XCD stripe swizzle (bid&7).
// ACT: 0=none 1=relu 2=sigmoid.
// WMODE 0: bf16 C0u[m*ldc+n]                              (he / hd scratch)
// WMODE 1: f32 C1f[((gm>>6)*512+n)*64+(gm&63)] (gm=m0+m)  (mu_logvar_2d out1)
//          + bf16 C0u[m*256+n] for n<256                  (compact mu scratch)
// WMODE 2: f32 unpatchify scatter into C0f = (B,C,H,W), rows gm=m0+m
template <int ACT, int WMODE>
__global__ void __launch_bounds__(512, 2)
gemm_bt(const unsigned short* __restrict__ A, int lda,
        const unsigned short* __restrict__ Bt,
        const float* __restrict__ bias,
        unsigned short* __restrict__ C0u,
        float* __restrict__ C0f,
        float* __restrict__ C1f,
        int ldc, int Kd, int nbn, int m0) {
    __shared__ __align__(16) unsigned short As[2][256 * 32];
    __shared__ __align__(16) unsigned short Bs[2][256 * 32];
    const int nbm = gridDim.x / nbn;
    const int stripe = nbm >> 3;                 // bm rows per XCD
    const int xcd = blockIdx.x & 7;
    const int loc = blockIdx.x >> 3;
    const int bm = xcd * stripe + (loc % stripe);
    const int bn = loc / stripe;
    const int tid = threadIdx.x;                 // 0..511
    const int wave = tid >> 6;                   // 0..7
    const int lane = tid & 63;
    const int wm = (wave >> 1) << 6;             // 0,64,128,192
    const int wn = (wave & 1) << 7;              // 0,128
    // staging: wave w, inst i covers rows i*128 + w*16 + (lane>>2),
    // phys slot group lane&3; fetched logical k-group g = (slot - row>>1)&3.
    const int srow = (wave << 4) + (lane >> 2);
    const int spg  = lane & 3;
    const unsigned short* Ab = A + (long)(bm * 256) * lda;
    const unsigned short* Bb = Bt + (long)(bn * 256) * Kd;

    f32x4_t acc[4][8];
    #pragma unroll
    for (int i = 0; i < 4; ++i)
        #pragma unroll
        for (int j = 0; j < 8; ++j)
            acc[i][j] = (f32x4_t){0.f, 0.f, 0.f, 0.f};

    const int fr = lane & 15;            // fragment row (m for A, n for B)
    const int quad = lane >> 4;          // k-group (8 elems) within BK=32

#define STAGE(p, k0)                                                         \
    {                                                                        \
        _Pragma("unroll")                                                    \
        for (int i_ = 0; i_ < 2; ++i_) {                                     \
            const int row_ = srow + (i_ << 7);                               \
            const int g_ = ((spg - (row_ >> 1)) & 3) << 3;                   \
            load_lds16(Ab + (long)row_ * lda + (k0) + g_,                    \
                       &As[p][((i_ << 7) + (wave << 4)) << 5]);              \
            load_lds16(Bb + (long)row_ * Kd + (k0) + g_,                     \
                       &Bs[p][((i_ << 7) + (wave << 4)) << 5]);              \
        }                                                                    \
    }

    const int iters = Kd >> 5;
    STAGE(0, 0);
    __syncthreads();
    for (int it = 0; it < iters; ++it) {
        const int p = it & 1;
        if (it + 1 < iters) STAGE(p ^ 1, (it + 1) << 5);   // prefetch next
        const unsigned short* Ap = As[p];
        const unsigned short* Bp = Bs[p];
        bf16x8_t af[4], bfr[8];
        #pragma unroll
        for (int i = 0; i < 4; ++i) {
            const int row = wm + (i << 4) + fr;
            const int pg = ((quad + (row >> 1)) & 3) << 3;
            af[i] = *(const bf16x8_t*)&Ap[(row << 5) + pg];
        }
        #pragma unroll
        for (int j = 0; j < 8; ++j) {
            const int row = wn + (j << 4) + fr;
            const int pg = ((quad + (row >> 1)) & 3) << 3;
            bfr[j] = *(const bf16x8_t*)&Bp[(row << 5) + pg];
        }
        #pragma unroll
        for (int i = 0; i < 4; ++i)
            #pragma unroll
            for (int j = 0; j < 8; ++j)
                acc[i][j] = __builtin_amdgcn_mfma_f32_16x16x32_bf16(
                    af[i], bfr[j], acc[i][j], 0, 0, 0);
        __syncthreads();   // next buf staged (overlapped) + cur reads done
    }
#undef STAGE

    // epilogue — C/D layout: col = lane&15, row = (lane>>4)*4 + reg
    const int gcol0 = bn * 256 + wn;
    const int grow0 = bm * 256 + wm;
    #pragma unroll
    for (int j = 0; j < 8; ++j) {
        const int n = gcol0 + (j << 4) + fr;
        const float bv = bias[n];
        #pragma unroll
        for (int i = 0; i < 4; ++i) {
            #pragma unroll
            for (int r = 0; r < 4; ++r) {
                const int m = grow0 + (i << 4) + (quad << 2) + r;
                float v = acc[i][j][r] + bv;
                if (ACT == 1) v = fmaxf(v, 0.f);
                if (ACT == 2) v = 1.f / (1.f + __expf(-v));
                if (WMODE == 0) {
                    C0u[(long)m * ldc + n] = f2bf(v);
                } else if (WMODE == 1) {
                    const int gm = m0 + m;
                    C1f[((long)(gm >> 6) * 512 + n) * 64 + (gm & 63)] = v;
                    if (n < 256) C0u[(long)m * 256 + n] = f2bf(v);
                } else {
                    const int gm = m0 + m;
                    const int b = gm >> 6, g6 = gm & 63;
                    const int gh = g6 >> 3, gw = g6 & 7;
                    const int c = n >> 8, kh = (n >> 4) & 15, kw = n & 15;
                    const long o = (long)(b * 3 + c) * 16384
                                 + ((gh << 4) + kh) * 128 + (gw << 4) + kw;
                    C0f[o] = v;
                }
            }
        }
    }
}

// ---------- launch ----------
extern "C" void kernel_launch(void* const* d_in, const int* in_sizes, int n_in,
                              void* d_out, int out_size, void* d_ws, size_t ws_size,
                              hipStream_t stream) {
    const float* x      = (const float*)d_in[0];
    const float* w_enc1 = (const float*)d_in[1];
    const float* b_enc1 = (const float*)d_in[2];
    const float* w_enc2 = (const float*)d_in[3];
    const float* b_enc2 = (const float*)d_in[4];
    const float* w_dec1 = (const float*)d_in[5];
    const float* b_dec1 = (const float*)d_in[6];
    const float* w_dec2 = (const float*)d_in[7];
    const float* b_dec2 = (const float*)d_in[8];
    float* outf = (float*)d_out;                      // f32 output
    unsigned short* patches = (unsigned short*)d_out; // patches bf16 in out0 u16 view
    float* out_ml = outf + (long)MM * PP;             // f32 [12.58M, 20.97M)

    // Scratch: prefer d_ws (single 16384-row chunk); else fall back to x's
    // dead buffer with two 8192-row chunks in REVERSE order.
    const size_t WT_ELEMS = 2048 * 768 + 512 * 2048 + 2048 * 256 + 768 * 2048;
    unsigned short* sb;
    long Mc;
    if (ws_size >= (WT_ELEMS + (size_t)MM * (LL + HID)) * 2) {
        sb = (unsigned short*)d_ws;  Mc = MM;         // 16384 rows, 1 chunk
    } else {
        sb = (unsigned short*)d_in[0]; Mc = 8192;     // x-buffer, 2 chunks
    }
    unsigned short* wT1 = sb;                         // 2048*768
    unsigned short* wT2 = wT1 + 2048 * 768;           // 512*2048
    unsigned short* wT3 = wT2 + 512 * 2048;           // 2048*256
    unsigned short* wT4 = wT3 + 2048 * 256;           // 768*2048
    unsigned short* mu  = wT4 + 768 * 2048;           // Mc*256
    unsigned short* he  = mu + Mc * LL;               // Mc*2048 (hd aliases he)

    patchify<<<6144, 256, 0, stream>>>(x, patches);

    transpose_k<<<(768 / 32) * (2048 / 32), 256, 0, stream>>>(w_enc1, wT1, 768, 2048);
    transpose_k<<<(2048 / 32) * (512 / 32), 256, 0, stream>>>(w_enc2, wT2, 2048, 512);
    transpose_k<<<(256 / 32) * (2048 / 32), 256, 0, stream>>>(w_dec1, wT3, 256, 2048);
    transpose_k<<<(2048 / 32) * (768 / 32), 256, 0, stream>>>(w_dec2, wT4, 2048, 768);

    const int nbm = (int)(Mc / 256);   // 64 or 32, divisible by 8
    for (long m0 = MM - Mc; m0 >= 0; m0 -= Mc) {
        // he = relu(patches[m0:] @ w_enc1 + b_enc1)      Mc x 2048, K=768
        gemm_bt<1, 0><<<nbm * (HID / 256), 512, 0, stream>>>(
            patches + m0 * PP, PP, wT1, b_enc1,
            he, nullptr, nullptr, HID, PP, HID / 256, 0);
        // ml = he @ w_enc2 + b_enc2 -> out1 f32 (transposed) + compact bf16 mu
        gemm_bt<0, 1><<<nbm * (512 / 256), 512, 0, stream>>>(
            he, HID, wT2, b_enc2,
            mu, nullptr, out_ml, 0, HID, 512 / 256, (int)m0);
        // hd = relu(mu @ w_dec1 + b_dec1)                Mc x 2048, K=256
        gemm_bt<1, 0><<<nbm * (HID / 256), 512, 0, stream>>>(
            mu, LL, wT3, b_dec1,
            he, nullptr, nullptr, HID, LL, HID / 256, 0);
        // recon rows m0.. = sigmoid(hd @ w_dec2 + b_dec2) -> f32 scatter out0
        gemm_bt<2, 2><<<nbm * (PP / 256), 512, 0, stream>>>(
            he, HID, wT4, b_dec2,
            nullptr, outf, nullptr, 0, HID, PP / 256, (int)m0);
    }
}